// Round 11
// baseline (254.701 us; speedup 1.0000x reference)
//
#include <hip/hip_runtime.h>
#include <hip/hip_bf16.h>

#define NN 50000
#define EE 600000
#define DD 128
#define LL 3
#define LN_EPS 1e-5f
#define CAP 64                      // bucket capacity; max in-degree ~30 for this graph
#define ALD 136                     // padded LDS row stride (shorts)
#define POOL 128                    // nodes per aggemm block

typedef __attribute__((ext_vector_type(8))) short short8;
typedef __attribute__((ext_vector_type(4))) float floatx4;

__device__ inline unsigned short f2bf(float f) {
    union { float f; unsigned u; } a; a.f = f;
    unsigned r = a.u + 0x7fffu + ((a.u >> 16) & 1u);  // RNE (finite values)
    return (unsigned short)(r >> 16);
}

// ------- fill: bucket CSR (hist+fill one pass) + W -> Wt bf16 conversion ----

__global__ void fill_kernel(const int* __restrict__ src, const int* __restrict__ dst,
                            const float* __restrict__ W, unsigned short* __restrict__ Wt,
                            int* __restrict__ cnt, int* __restrict__ csrc) {
    int i = blockIdx.x * blockDim.x + threadIdx.x;
    if (i < LL * DD * DD) {   // Wt[l][n][k] = bf16(W[l][k][n])
        int l = i >> 14, n = (i >> 7) & 127, k = i & 127;
        Wt[i] = f2bf(W[(l << 14) + k * DD + n]);
    }
    if (i >= EE) return;
    int d = dst[i];
    int pos = atomicAdd(&cnt[d], 1);
    csrc[(size_t)d * CAP + pos] = src[i];
}

// ---------------- gemm0: Tb[n] = bf16(dinv[n] * (x[n] @ W0)) ----------------
// 32 rows/block, 256 threads = 4 waves. Wave w: rows (w>>1)*16, cols (w&1)*64.

__global__ __launch_bounds__(256) void gemm0_kernel(const float* __restrict__ A,
                                                    const unsigned short* __restrict__ Wt,
                                                    const int* __restrict__ cnt,
                                                    unsigned short* __restrict__ Cb) {
    __shared__ unsigned short alds[32 * ALD];
    int tid = threadIdx.x;
    int lane = tid & 63;
    int w = tid >> 6;
    int rowbase = blockIdx.x * 32;

    int cbase = (w & 1) * 64;
    int nIdx = cbase + (lane & 15);
    int kq = (lane >> 4) * 8;

    {
        int r = tid >> 3;
        int k0 = (tid & 7) * 16;
        int grow = rowbase + r;
        unsigned short* dstp = &alds[r * ALD + k0];
        if (grow < NN) {
            const float* ap = &A[(size_t)grow * DD + k0];
            float4 v0 = *(const float4*)&ap[0];
            float4 v1 = *(const float4*)&ap[4];
            float4 v2 = *(const float4*)&ap[8];
            float4 v3 = *(const float4*)&ap[12];
            float fv[16] = {v0.x,v0.y,v0.z,v0.w, v1.x,v1.y,v1.z,v1.w,
                            v2.x,v2.y,v2.z,v2.w, v3.x,v3.y,v3.z,v3.w};
            unsigned short uv[16];
            #pragma unroll
            for (int q = 0; q < 16; q++) uv[q] = f2bf(fv[q]);
            *(uint4*)&dstp[0] = *(uint4*)&uv[0];
            *(uint4*)&dstp[8] = *(uint4*)&uv[8];
        } else {
            uint4 z = make_uint4(0, 0, 0, 0);
            *(uint4*)&dstp[0] = z;
            *(uint4*)&dstp[8] = z;
        }
    }
    __syncthreads();

    int rbase = (w >> 1) * 16;
    int mrow = rbase + (lane & 15);
    floatx4 acc[4] = {{0.f,0.f,0.f,0.f},{0.f,0.f,0.f,0.f},
                      {0.f,0.f,0.f,0.f},{0.f,0.f,0.f,0.f}};
    #pragma unroll
    for (int t = 0; t < 4; t++) {
        short8 a = *(const short8*)&alds[mrow * ALD + t * 32 + kq];
        #pragma unroll
        for (int j = 0; j < 4; j++) {
            short8 b = *(const short8*)&Wt[(nIdx + j * 16) * DD + t * 32 + kq];
            acc[j] = __builtin_amdgcn_mfma_f32_16x16x32_bf16(a, b, acc[j], 0, 0, 0);
        }
    }

    int gnode0 = rowbase + rbase + (lane >> 4) * 4;
    #pragma unroll
    for (int i = 0; i < 4; i++) {
        int node = gnode0 + i;
        if (node < NN) {
            float dv = rsqrtf((float)(cnt[node] + 1));
            #pragma unroll
            for (int j = 0; j < 4; j++)
                Cb[(size_t)node * DD + cbase + j * 16 + (lane & 15)] = f2bf(acc[j][i] * dv);
        }
    }
}

// --------- shared agg helper: aggregate+bias+LN+PReLU for one node ----------
// 16-lane group; lane owns features [8l,8l+8). Returns yv[8] (f32).

__device__ inline void acc_row(float* acc, uint4 t) {
    unsigned uu[4] = {t.x, t.y, t.z, t.w};
    #pragma unroll
    for (int q = 0; q < 4; q++) {
        union { unsigned x; float f; } lo, hi;
        lo.x = uu[q] << 16;
        hi.x = uu[q] & 0xffff0000u;
        acc[2 * q]     += lo.f;
        acc[2 * q + 1] += hi.f;
    }
}

__device__ inline void agg_node(const unsigned short* __restrict__ Tb,
                                const int* __restrict__ cnt, const int* __restrict__ csrc,
                                const float* bv, const float* wv, const float* cv,
                                float alpha, int node, int f8, float* yv) {
    int deg = cnt[node];
    float dv = rsqrtf((float)(deg + 1));
    const int* row = &csrc[(size_t)node * CAP];

    float acc[8] = {};
    acc_row(acc, *(const uint4*)&Tb[(size_t)node * DD + f8]);  // self-loop (prescaled row)

    int k = 0;
    for (; k + 4 <= deg; k += 4) {
        int4 ss = *(const int4*)&row[k];
        uint4 t0 = *(const uint4*)&Tb[(size_t)ss.x * DD + f8];
        uint4 t1 = *(const uint4*)&Tb[(size_t)ss.y * DD + f8];
        uint4 t2 = *(const uint4*)&Tb[(size_t)ss.z * DD + f8];
        uint4 t3 = *(const uint4*)&Tb[(size_t)ss.w * DD + f8];
        acc_row(acc, t0); acc_row(acc, t1); acc_row(acc, t2); acc_row(acc, t3);
    }
    for (; k < deg; k++) {
        acc_row(acc, *(const uint4*)&Tb[(size_t)row[k] * DD + f8]);
    }

    float a[8];
    float s1 = 0.f, s2 = 0.f;
    #pragma unroll
    for (int q = 0; q < 8; q++) {
        a[q] = fmaf(acc[q], dv, bv[q]);
        s1 += a[q]; s2 += a[q] * a[q];
    }
    #pragma unroll
    for (int off = 8; off > 0; off >>= 1) {
        s1 += __shfl_xor(s1, off, 16);
        s2 += __shfl_xor(s2, off, 16);
    }
    float mu = s1 * (1.f / DD);
    float var = s2 * (1.f / DD) - mu * mu;
    float rstd = rsqrtf(var + LN_EPS);
    #pragma unroll
    for (int q = 0; q < 8; q++) {
        float y = (a[q] - mu) * rstd * wv[q] + cv[q];
        yv[q] = (y >= 0.f) ? y : alpha * y;
    }
}

// ------- fused agg(layer l) + gemm(layer l+1): Tb -> Tout (both prescaled) --
// 512 threads; 128-node pool; 32 groups x 16 lanes grab nodes dynamically from
// an LDS counter (balances the pre-barrier gather). MFMA: 8 waves, each a
// 16-row stripe x 128 cols of the 128x128 tile.

__global__ __launch_bounds__(512) void aggemm_kernel(
    const unsigned short* __restrict__ Tb, const int* __restrict__ cnt,
    const int* __restrict__ csrc,
    const float* __restrict__ bias, const float* __restrict__ lnw,
    const float* __restrict__ lnb, const float* __restrict__ alphas, int layer,
    const unsigned short* __restrict__ Wt, unsigned short* __restrict__ Tout) {
    __shared__ unsigned short alds[POOL * ALD];
    __shared__ int nextslot;
    int tid = threadIdx.x;
    int lane16 = tid & 15;
    int f8 = lane16 * 8;
    int nodebase = blockIdx.x * POOL;
    if (tid == 0) nextslot = 0;

    float4 b0 = *(const float4*)&bias[f8];
    float4 b1 = *(const float4*)&bias[f8 + 4];
    float4 w0 = *(const float4*)&lnw[f8];
    float4 w1 = *(const float4*)&lnw[f8 + 4];
    float4 c0 = *(const float4*)&lnb[f8];
    float4 c1 = *(const float4*)&lnb[f8 + 4];
    float bv[8] = {b0.x, b0.y, b0.z, b0.w, b1.x, b1.y, b1.z, b1.w};
    float wv[8] = {w0.x, w0.y, w0.z, w0.w, w1.x, w1.y, w1.z, w1.w};
    float cv[8] = {c0.x, c0.y, c0.z, c0.w, c1.x, c1.y, c1.z, c1.w};
    float alpha = alphas[layer];
    __syncthreads();

    for (;;) {
        int sv = 0;
        if (lane16 == 0) sv = atomicAdd(&nextslot, 1);
        int s = __shfl(sv, 0, 16);      // broadcast within the 16-lane group
        if (s >= POOL) break;
        int node = nodebase + s;
        unsigned short* dstp = &alds[s * ALD + f8];
        if (node < NN) {
            float yv[8];
            agg_node(Tb, cnt, csrc, bv, wv, cv, alpha, node, f8, yv);
            unsigned short pv[8];
            #pragma unroll
            for (int q = 0; q < 8; q++) pv[q] = f2bf(yv[q]);
            *(uint4*)dstp = *(uint4*)&pv[0];
        } else {
            *(uint4*)dstp = make_uint4(0, 0, 0, 0);
        }
    }
    __syncthreads();

    // MFMA: C = Y @ W_{l+1}, epilogue prescale by dinv.
    int lane = tid & 63;
    int w = tid >> 6;                 // 0..7
    int rbase = w * 16;
    int kq = (lane >> 4) * 8;
    int mrow = rbase + (lane & 15);
    int nIdx = lane & 15;
    floatx4 acc[8] = {{0.f,0.f,0.f,0.f},{0.f,0.f,0.f,0.f},{0.f,0.f,0.f,0.f},
                      {0.f,0.f,0.f,0.f},{0.f,0.f,0.f,0.f},{0.f,0.f,0.f,0.f},
                      {0.f,0.f,0.f,0.f},{0.f,0.f,0.f,0.f}};
    #pragma unroll
    for (int t = 0; t < 4; t++) {
        short8 a = *(const short8*)&alds[mrow * ALD + t * 32 + kq];
        #pragma unroll
        for (int j = 0; j < 8; j++) {
            short8 b = *(const short8*)&Wt[(nIdx + j * 16) * DD + t * 32 + kq];
            acc[j] = __builtin_amdgcn_mfma_f32_16x16x32_bf16(a, b, acc[j], 0, 0, 0);
        }
    }
    int gnode0 = nodebase + rbase + (lane >> 4) * 4;
    #pragma unroll
    for (int i = 0; i < 4; i++) {
        int node = gnode0 + i;
        if (node < NN) {
            float dv = rsqrtf((float)(cnt[node] + 1));
            #pragma unroll
            for (int j = 0; j < 8; j++)
                Tout[(size_t)node * DD + j * 16 + (lane & 15)] = f2bf(acc[j][i] * dv);
        }
    }
}

// ---------------- final agg: layer 2, f32 output ----------------
// 256 threads = 16 groups of 16 lanes; group g handles node blockIdx*16+g.
// No barrier at the end -> no straggler tax; keep max-TLP shape.

__global__ __launch_bounds__(256) void agg_final_kernel(
    const unsigned short* __restrict__ Tb, const int* __restrict__ cnt,
    const int* __restrict__ csrc,
    const float* __restrict__ bias, const float* __restrict__ lnw,
    const float* __restrict__ lnb, const float* __restrict__ alphas, int layer,
    float* __restrict__ out) {
    int g = threadIdx.x >> 4;
    int lane16 = threadIdx.x & 15;
    int f8 = lane16 * 8;
    int node = blockIdx.x * 16 + g;
    if (node >= NN) return;

    float4 b0 = *(const float4*)&bias[f8];
    float4 b1 = *(const float4*)&bias[f8 + 4];
    float4 w0 = *(const float4*)&lnw[f8];
    float4 w1 = *(const float4*)&lnw[f8 + 4];
    float4 c0 = *(const float4*)&lnb[f8];
    float4 c1 = *(const float4*)&lnb[f8 + 4];
    float bv[8] = {b0.x, b0.y, b0.z, b0.w, b1.x, b1.y, b1.z, b1.w};
    float wv[8] = {w0.x, w0.y, w0.z, w0.w, w1.x, w1.y, w1.z, w1.w};
    float cv[8] = {c0.x, c0.y, c0.z, c0.w, c1.x, c1.y, c1.z, c1.w};

    float yv[8];
    agg_node(Tb, cnt, csrc, bv, wv, cv, alphas[layer], node, f8, yv);

    float* op = &out[(size_t)node * DD + f8];
    *(float4*)&op[0] = make_float4(yv[0], yv[1], yv[2], yv[3]);
    *(float4*)&op[4] = make_float4(yv[4], yv[5], yv[6], yv[7]);
}

// ---------------- launch ----------------

extern "C" void kernel_launch(void* const* d_in, const int* in_sizes, int n_in,
                              void* d_out, int out_size, void* d_ws, size_t ws_size,
                              hipStream_t stream) {
    const float* x    = (const float*)d_in[0];
    const int*   ei   = (const int*)d_in[1];
    const float* Ws   = (const float*)d_in[2];
    const float* bs   = (const float*)d_in[3];
    const float* lnw  = (const float*)d_in[4];
    const float* lnb  = (const float*)d_in[5];
    const float* alphas = (const float*)d_in[6];
    float* out = (float*)d_out;

    const int* src = ei;
    const int* dst = ei + EE;

    char* ws = (char*)d_ws;
    size_t off = 0;
    auto alloc = [&](size_t bytes) -> void* {
        void* p = ws + off;
        off = (off + bytes + 255) & ~(size_t)255;
        return p;
    };
    int* cnt  = (int*)alloc(NN * sizeof(int));
    int* csrc = (int*)alloc((size_t)NN * CAP * sizeof(int));
    unsigned short* wt    = (unsigned short*)alloc((size_t)LL * DD * DD * sizeof(unsigned short));
    unsigned short* tbufA = (unsigned short*)alloc((size_t)NN * DD * sizeof(unsigned short));
    unsigned short* tbufB = (unsigned short*)alloc((size_t)NN * DD * sizeof(unsigned short));

    hipMemsetAsync(cnt, 0, NN * sizeof(int), stream);
    fill_kernel<<<(EE + 255) / 256, 256, 0, stream>>>(src, dst, Ws, wt, cnt, csrc);

    gemm0_kernel<<<(NN + 31) / 32, 256, 0, stream>>>(x, wt, cnt, tbufA);

    const int agg_grid = (NN + POOL - 1) / POOL;   // 391
    aggemm_kernel<<<agg_grid, 512, 0, stream>>>(tbufA, cnt, csrc,
                                                bs + 0 * DD, lnw + 0 * DD, lnb + 0 * DD,
                                                alphas, 0, wt + 1 * DD * DD, tbufB);
    aggemm_kernel<<<agg_grid, 512, 0, stream>>>(tbufB, cnt, csrc,
                                                bs + 1 * DD, lnw + 1 * DD, lnb + 1 * DD,
                                                alphas, 1, wt + 2 * DD * DD, tbufA);
    agg_final_kernel<<<(NN + 15) / 16, 256, 0, stream>>>(tbufA, cnt, csrc,
                                                         bs + 2 * DD, lnw + 2 * DD, lnb + 2 * DD,
                                                         alphas, 2, out);
}

// Round 12
// 243.555 us; speedup vs baseline: 1.0458x; 1.0458x over previous
//
#include <hip/hip_runtime.h>
#include <hip/hip_bf16.h>

#define NN 50000
#define EE 600000
#define DD 128
#define LL 3
#define LN_EPS 1e-5f
#define CAP 64                      // bucket capacity; max in-degree ~30 for this graph
#define ALD 136                     // padded LDS row stride (shorts)
#define POOL 16                     // nodes per aggemm block (NN = 3125 * 16 exactly)

typedef __attribute__((ext_vector_type(8))) short short8;
typedef __attribute__((ext_vector_type(4))) float floatx4;

__device__ inline unsigned short f2bf(float f) {
    union { float f; unsigned u; } a; a.f = f;
    unsigned r = a.u + 0x7fffu + ((a.u >> 16) & 1u);  // RNE (finite values)
    return (unsigned short)(r >> 16);
}

// ------- fill: bucket CSR (hist+fill one pass) + W -> Wt bf16 conversion ----

__global__ void fill_kernel(const int* __restrict__ src, const int* __restrict__ dst,
                            const float* __restrict__ W, unsigned short* __restrict__ Wt,
                            int* __restrict__ cnt, int* __restrict__ csrc) {
    int i = blockIdx.x * blockDim.x + threadIdx.x;
    if (i < LL * DD * DD) {   // Wt[l][n][k] = bf16(W[l][k][n])
        int l = i >> 14, n = (i >> 7) & 127, k = i & 127;
        Wt[i] = f2bf(W[(l << 14) + k * DD + n]);
    }
    if (i >= EE) return;
    int d = dst[i];
    int pos = atomicAdd(&cnt[d], 1);
    csrc[(size_t)d * CAP + pos] = src[i];
}

// ---------------- gemm0: Tb[n] = bf16(dinv[n] * (x[n] @ W0)) ----------------
// 32 rows/block, 256 threads = 4 waves. Wave w: rows (w>>1)*16, cols (w&1)*64.

__global__ __launch_bounds__(256) void gemm0_kernel(const float* __restrict__ A,
                                                    const unsigned short* __restrict__ Wt,
                                                    const int* __restrict__ cnt,
                                                    unsigned short* __restrict__ Cb) {
    __shared__ unsigned short alds[32 * ALD];
    int tid = threadIdx.x;
    int lane = tid & 63;
    int w = tid >> 6;
    int rowbase = blockIdx.x * 32;

    int cbase = (w & 1) * 64;
    int nIdx = cbase + (lane & 15);
    int kq = (lane >> 4) * 8;

    {
        int r = tid >> 3;
        int k0 = (tid & 7) * 16;
        int grow = rowbase + r;
        unsigned short* dstp = &alds[r * ALD + k0];
        if (grow < NN) {
            const float* ap = &A[(size_t)grow * DD + k0];
            float4 v0 = *(const float4*)&ap[0];
            float4 v1 = *(const float4*)&ap[4];
            float4 v2 = *(const float4*)&ap[8];
            float4 v3 = *(const float4*)&ap[12];
            float fv[16] = {v0.x,v0.y,v0.z,v0.w, v1.x,v1.y,v1.z,v1.w,
                            v2.x,v2.y,v2.z,v2.w, v3.x,v3.y,v3.z,v3.w};
            unsigned short uv[16];
            #pragma unroll
            for (int q = 0; q < 16; q++) uv[q] = f2bf(fv[q]);
            *(uint4*)&dstp[0] = *(uint4*)&uv[0];
            *(uint4*)&dstp[8] = *(uint4*)&uv[8];
        } else {
            uint4 z = make_uint4(0, 0, 0, 0);
            *(uint4*)&dstp[0] = z;
            *(uint4*)&dstp[8] = z;
        }
    }
    __syncthreads();

    int rbase = (w >> 1) * 16;
    int mrow = rbase + (lane & 15);
    floatx4 acc[4] = {{0.f,0.f,0.f,0.f},{0.f,0.f,0.f,0.f},
                      {0.f,0.f,0.f,0.f},{0.f,0.f,0.f,0.f}};
    #pragma unroll
    for (int t = 0; t < 4; t++) {
        short8 a = *(const short8*)&alds[mrow * ALD + t * 32 + kq];
        #pragma unroll
        for (int j = 0; j < 4; j++) {
            short8 b = *(const short8*)&Wt[(nIdx + j * 16) * DD + t * 32 + kq];
            acc[j] = __builtin_amdgcn_mfma_f32_16x16x32_bf16(a, b, acc[j], 0, 0, 0);
        }
    }

    int gnode0 = rowbase + rbase + (lane >> 4) * 4;
    #pragma unroll
    for (int i = 0; i < 4; i++) {
        int node = gnode0 + i;
        if (node < NN) {
            float dv = rsqrtf((float)(cnt[node] + 1));
            #pragma unroll
            for (int j = 0; j < 4; j++)
                Cb[(size_t)node * DD + cbase + j * 16 + (lane & 15)] = f2bf(acc[j][i] * dv);
        }
    }
}

// --------- shared agg helper: aggregate+bias+LN+PReLU for one node ----------
// 16-lane group; lane owns features [8l,8l+8). Returns yv[8] (f32).

__device__ inline void acc_row(float* acc, uint4 t) {
    unsigned uu[4] = {t.x, t.y, t.z, t.w};
    #pragma unroll
    for (int q = 0; q < 4; q++) {
        union { unsigned x; float f; } lo, hi;
        lo.x = uu[q] << 16;
        hi.x = uu[q] & 0xffff0000u;
        acc[2 * q]     += lo.f;
        acc[2 * q + 1] += hi.f;
    }
}

__device__ inline void agg_node(const unsigned short* __restrict__ Tb,
                                const int* __restrict__ cnt, const int* __restrict__ csrc,
                                const float* bv, const float* wv, const float* cv,
                                float alpha, int node, int f8, float* yv) {
    int deg = cnt[node];
    float dv = rsqrtf((float)(deg + 1));
    const int* row = &csrc[(size_t)node * CAP];

    float acc[8] = {};
    acc_row(acc, *(const uint4*)&Tb[(size_t)node * DD + f8]);  // self-loop (prescaled row)

    int k = 0;
    for (; k + 4 <= deg; k += 4) {
        int4 ss = *(const int4*)&row[k];
        uint4 t0 = *(const uint4*)&Tb[(size_t)ss.x * DD + f8];
        uint4 t1 = *(const uint4*)&Tb[(size_t)ss.y * DD + f8];
        uint4 t2 = *(const uint4*)&Tb[(size_t)ss.z * DD + f8];
        uint4 t3 = *(const uint4*)&Tb[(size_t)ss.w * DD + f8];
        acc_row(acc, t0); acc_row(acc, t1); acc_row(acc, t2); acc_row(acc, t3);
    }
    for (; k < deg; k++) {
        acc_row(acc, *(const uint4*)&Tb[(size_t)row[k] * DD + f8]);
    }

    float a[8];
    float s1 = 0.f, s2 = 0.f;
    #pragma unroll
    for (int q = 0; q < 8; q++) {
        a[q] = fmaf(acc[q], dv, bv[q]);
        s1 += a[q]; s2 += a[q] * a[q];
    }
    #pragma unroll
    for (int off = 8; off > 0; off >>= 1) {
        s1 += __shfl_xor(s1, off, 16);
        s2 += __shfl_xor(s2, off, 16);
    }
    float mu = s1 * (1.f / DD);
    float var = s2 * (1.f / DD) - mu * mu;
    float rstd = rsqrtf(var + LN_EPS);
    #pragma unroll
    for (int q = 0; q < 8; q++) {
        float y = (a[q] - mu) * rstd * wv[q] + cv[q];
        yv[q] = (y >= 0.f) ? y : alpha * y;
    }
}

// ------- fused agg(layer l) + gemm(layer l+1): Tb -> Tout (both prescaled) --
// 256 threads, 16 nodes/block (= 3125 blocks, 12.5k waves: max TLP for the
// gather). 16 groups x 16 lanes, one node per group. MFMA: 4 waves, wave w
// computes the 16-row x 32-col slice (cbase = w*32).

__global__ __launch_bounds__(256) void aggemm_kernel(
    const unsigned short* __restrict__ Tb, const int* __restrict__ cnt,
    const int* __restrict__ csrc,
    const float* __restrict__ bias, const float* __restrict__ lnw,
    const float* __restrict__ lnb, const float* __restrict__ alphas, int layer,
    const unsigned short* __restrict__ Wt, unsigned short* __restrict__ Tout) {
    __shared__ unsigned short alds[POOL * ALD];
    int tid = threadIdx.x;
    int g = tid >> 4;          // 0..15: group = local row
    int lane16 = tid & 15;
    int f8 = lane16 * 8;
    int nodebase = blockIdx.x * POOL;

    float4 b0 = *(const float4*)&bias[f8];
    float4 b1 = *(const float4*)&bias[f8 + 4];
    float4 w0 = *(const float4*)&lnw[f8];
    float4 w1 = *(const float4*)&lnw[f8 + 4];
    float4 c0 = *(const float4*)&lnb[f8];
    float4 c1 = *(const float4*)&lnb[f8 + 4];
    float bv[8] = {b0.x, b0.y, b0.z, b0.w, b1.x, b1.y, b1.z, b1.w};
    float wv[8] = {w0.x, w0.y, w0.z, w0.w, w1.x, w1.y, w1.z, w1.w};
    float cv[8] = {c0.x, c0.y, c0.z, c0.w, c1.x, c1.y, c1.z, c1.w};
    float alpha = alphas[layer];

    {   // NN == 3125*16: node always in range
        int node = nodebase + g;
        float yv[8];
        agg_node(Tb, cnt, csrc, bv, wv, cv, alpha, node, f8, yv);
        unsigned short pv[8];
        #pragma unroll
        for (int q = 0; q < 8; q++) pv[q] = f2bf(yv[q]);
        *(uint4*)&alds[g * ALD + f8] = *(uint4*)&pv[0];
    }
    __syncthreads();

    // MFMA: C = Y @ W_{l+1}, epilogue prescale by dinv. 4 waves, 16x32 each.
    int lane = tid & 63;
    int w = tid >> 6;                 // 0..3
    int cbase = w * 32;
    int kq = (lane >> 4) * 8;
    int mrow = lane & 15;
    floatx4 acc[2] = {{0.f,0.f,0.f,0.f},{0.f,0.f,0.f,0.f}};
    #pragma unroll
    for (int t = 0; t < 4; t++) {
        short8 a = *(const short8*)&alds[mrow * ALD + t * 32 + kq];
        #pragma unroll
        for (int j = 0; j < 2; j++) {
            short8 b = *(const short8*)&Wt[(cbase + j * 16 + (lane & 15)) * DD + t * 32 + kq];
            acc[j] = __builtin_amdgcn_mfma_f32_16x16x32_bf16(a, b, acc[j], 0, 0, 0);
        }
    }
    int gnode0 = nodebase + (lane >> 4) * 4;
    #pragma unroll
    for (int i = 0; i < 4; i++) {
        int node = gnode0 + i;
        float dv = rsqrtf((float)(cnt[node] + 1));
        #pragma unroll
        for (int j = 0; j < 2; j++)
            Tout[(size_t)node * DD + cbase + j * 16 + (lane & 15)] = f2bf(acc[j][i] * dv);
    }
}

// ---------------- final agg: layer 2, f32 output ----------------
// 256 threads = 16 groups of 16 lanes; group g handles node blockIdx*16+g.
// No barrier -> no straggler tax; max-TLP shape.

__global__ __launch_bounds__(256) void agg_final_kernel(
    const unsigned short* __restrict__ Tb, const int* __restrict__ cnt,
    const int* __restrict__ csrc,
    const float* __restrict__ bias, const float* __restrict__ lnw,
    const float* __restrict__ lnb, const float* __restrict__ alphas, int layer,
    float* __restrict__ out) {
    int g = threadIdx.x >> 4;
    int lane16 = threadIdx.x & 15;
    int f8 = lane16 * 8;
    int node = blockIdx.x * 16 + g;
    if (node >= NN) return;

    float4 b0 = *(const float4*)&bias[f8];
    float4 b1 = *(const float4*)&bias[f8 + 4];
    float4 w0 = *(const float4*)&lnw[f8];
    float4 w1 = *(const float4*)&lnw[f8 + 4];
    float4 c0 = *(const float4*)&lnb[f8];
    float4 c1 = *(const float4*)&lnb[f8 + 4];
    float bv[8] = {b0.x, b0.y, b0.z, b0.w, b1.x, b1.y, b1.z, b1.w};
    float wv[8] = {w0.x, w0.y, w0.z, w0.w, w1.x, w1.y, w1.z, w1.w};
    float cv[8] = {c0.x, c0.y, c0.z, c0.w, c1.x, c1.y, c1.z, c1.w};

    float yv[8];
    agg_node(Tb, cnt, csrc, bv, wv, cv, alphas[layer], node, f8, yv);

    float* op = &out[(size_t)node * DD + f8];
    *(float4*)&op[0] = make_float4(yv[0], yv[1], yv[2], yv[3]);
    *(float4*)&op[4] = make_float4(yv[4], yv[5], yv[6], yv[7]);
}

// ---------------- launch ----------------

extern "C" void kernel_launch(void* const* d_in, const int* in_sizes, int n_in,
                              void* d_out, int out_size, void* d_ws, size_t ws_size,
                              hipStream_t stream) {
    const float* x    = (const float*)d_in[0];
    const int*   ei   = (const int*)d_in[1];
    const float* Ws   = (const float*)d_in[2];
    const float* bs   = (const float*)d_in[3];
    const float* lnw  = (const float*)d_in[4];
    const float* lnb  = (const float*)d_in[5];
    const float* alphas = (const float*)d_in[6];
    float* out = (float*)d_out;

    const int* src = ei;
    const int* dst = ei + EE;

    char* ws = (char*)d_ws;
    size_t off = 0;
    auto alloc = [&](size_t bytes) -> void* {
        void* p = ws + off;
        off = (off + bytes + 255) & ~(size_t)255;
        return p;
    };
    int* cnt  = (int*)alloc(NN * sizeof(int));
    int* csrc = (int*)alloc((size_t)NN * CAP * sizeof(int));
    unsigned short* wt    = (unsigned short*)alloc((size_t)LL * DD * DD * sizeof(unsigned short));
    unsigned short* tbufA = (unsigned short*)alloc((size_t)NN * DD * sizeof(unsigned short));
    unsigned short* tbufB = (unsigned short*)alloc((size_t)NN * DD * sizeof(unsigned short));

    hipMemsetAsync(cnt, 0, NN * sizeof(int), stream);
    fill_kernel<<<(EE + 255) / 256, 256, 0, stream>>>(src, dst, Ws, wt, cnt, csrc);

    gemm0_kernel<<<(NN + 31) / 32, 256, 0, stream>>>(x, wt, cnt, tbufA);

    const int agg_grid = NN / POOL;   // 3125
    aggemm_kernel<<<agg_grid, 256, 0, stream>>>(tbufA, cnt, csrc,
                                                bs + 0 * DD, lnw + 0 * DD, lnb + 0 * DD,
                                                alphas, 0, wt + 1 * DD * DD, tbufB);
    aggemm_kernel<<<agg_grid, 256, 0, stream>>>(tbufB, cnt, csrc,
                                                bs + 1 * DD, lnw + 1 * DD, lnb + 1 * DD,
                                                alphas, 1, wt + 2 * DD * DD, tbufA);
    agg_final_kernel<<<(NN + 15) / 16, 256, 0, stream>>>(tbufA, cnt, csrc,
                                                         bs + 2 * DD, lnw + 2 * DD, lnb + 2 * DD,
                                                         alphas, 2, out);
}

// Round 13
// 235.828 us; speedup vs baseline: 1.0800x; 1.0328x over previous
//
#include <hip/hip_runtime.h>
#include <hip/hip_bf16.h>

#define NN 50000
#define EE 600000
#define DD 128
#define LL 3
#define LN_EPS 1e-5f
#define CAP 64                      // bucket capacity; max in-degree ~30 for this graph
#define ALD 136                     // padded LDS row stride (shorts)
#define POOL 16                     // nodes per aggemm block (NN = 3125 * 16 exactly)
#define G0BLK ((NN + 31) / 32)      // 1563 blocks for gemm0_fill

typedef __attribute__((ext_vector_type(8))) short short8;
typedef __attribute__((ext_vector_type(4))) float floatx4;

__device__ inline unsigned short f2bf(float f) {
    union { float f; unsigned u; } a; a.f = f;
    unsigned r = a.u + 0x7fffu + ((a.u >> 16) & 1u);  // RNE (finite values)
    return (unsigned short)(r >> 16);
}

// ------- init: zero cnt + W -> Wt bf16 (Wt[l][n][k] = bf16(W[l][k][n])) -----

__global__ __launch_bounds__(256) void init_kernel(const float* __restrict__ W,
                                                   unsigned short* __restrict__ Wt,
                                                   int* __restrict__ cnt) {
    for (int i = blockIdx.x * 256 + threadIdx.x; i < NN; i += gridDim.x * 256)
        cnt[i] = 0;
    for (int i = blockIdx.x * 256 + threadIdx.x; i < LL * DD * DD; i += gridDim.x * 256) {
        int l = i >> 14, n = (i >> 7) & 127, k = i & 127;
        Wt[i] = f2bf(W[(l << 14) + k * DD + n]);
    }
}

// ------ gemm0_fill: bucket-CSR fill (grid-stride) + Tb = bf16(x @ W0) -------
// Fill needs to be complete only by the NEXT kernel (aggemm); gemm0's own
// output is unscaled, so no dependence on cnt. 32 rows/block, 256 thr.

__global__ __launch_bounds__(256) void gemm0_fill_kernel(
    const float* __restrict__ A, const unsigned short* __restrict__ Wt,
    const int* __restrict__ src, const int* __restrict__ dst,
    int* __restrict__ cnt, int* __restrict__ csrc,
    unsigned short* __restrict__ Cb) {
    __shared__ unsigned short alds[32 * ALD];
    int tid = threadIdx.x;

    // phase A: CSR fill, grid-stride over edges (independent of phase B)
    for (int e = blockIdx.x * 256 + tid; e < EE; e += G0BLK * 256) {
        int d = dst[e];
        int pos = atomicAdd(&cnt[d], 1);
        csrc[(size_t)d * CAP + pos] = src[e];
    }

    // phase B: GEMM tile (unscaled epilogue)
    int lane = tid & 63;
    int w = tid >> 6;
    int rowbase = blockIdx.x * 32;
    int cbase = (w & 1) * 64;
    int nIdx = cbase + (lane & 15);
    int kq = (lane >> 4) * 8;

    {
        int r = tid >> 3;
        int k0 = (tid & 7) * 16;
        int grow = rowbase + r;
        unsigned short* dstp = &alds[r * ALD + k0];
        if (grow < NN) {
            const float* ap = &A[(size_t)grow * DD + k0];
            float4 v0 = *(const float4*)&ap[0];
            float4 v1 = *(const float4*)&ap[4];
            float4 v2 = *(const float4*)&ap[8];
            float4 v3 = *(const float4*)&ap[12];
            float fv[16] = {v0.x,v0.y,v0.z,v0.w, v1.x,v1.y,v1.z,v1.w,
                            v2.x,v2.y,v2.z,v2.w, v3.x,v3.y,v3.z,v3.w};
            unsigned short uv[16];
            #pragma unroll
            for (int q = 0; q < 16; q++) uv[q] = f2bf(fv[q]);
            *(uint4*)&dstp[0] = *(uint4*)&uv[0];
            *(uint4*)&dstp[8] = *(uint4*)&uv[8];
        } else {
            uint4 z = make_uint4(0, 0, 0, 0);
            *(uint4*)&dstp[0] = z;
            *(uint4*)&dstp[8] = z;
        }
    }
    __syncthreads();

    int rbase = (w >> 1) * 16;
    int mrow = rbase + (lane & 15);
    floatx4 acc[4] = {{0.f,0.f,0.f,0.f},{0.f,0.f,0.f,0.f},
                      {0.f,0.f,0.f,0.f},{0.f,0.f,0.f,0.f}};
    #pragma unroll
    for (int t = 0; t < 4; t++) {
        short8 a = *(const short8*)&alds[mrow * ALD + t * 32 + kq];
        #pragma unroll
        for (int j = 0; j < 4; j++) {
            short8 b = *(const short8*)&Wt[(nIdx + j * 16) * DD + t * 32 + kq];
            acc[j] = __builtin_amdgcn_mfma_f32_16x16x32_bf16(a, b, acc[j], 0, 0, 0);
        }
    }

    int gnode0 = rowbase + rbase + (lane >> 4) * 4;
    #pragma unroll
    for (int i = 0; i < 4; i++) {
        int node = gnode0 + i;
        if (node < NN) {
            #pragma unroll
            for (int j = 0; j < 4; j++)
                Cb[(size_t)node * DD + cbase + j * 16 + (lane & 15)] = f2bf(acc[j][i]);
        }
    }
}

// --------- shared agg helper: aggregate+bias+LN+PReLU for one node ----------
// Tb is UNSCALED; per-edge weight w = rsqrt(cnt[s]+1), self term seeded dv*T.
// 16-lane group; lane owns features [8l,8l+8). Returns yv[8] (f32).

__device__ inline void acc_row_w(float* acc, uint4 t, float w) {
    unsigned uu[4] = {t.x, t.y, t.z, t.w};
    #pragma unroll
    for (int q = 0; q < 4; q++) {
        union { unsigned x; float f; } lo, hi;
        lo.x = uu[q] << 16;
        hi.x = uu[q] & 0xffff0000u;
        acc[2 * q]     += w * lo.f;
        acc[2 * q + 1] += w * hi.f;
    }
}

__device__ inline void agg_node(const unsigned short* __restrict__ Tb,
                                const int* __restrict__ cnt, const int* __restrict__ csrc,
                                const float* bv, const float* wv, const float* cv,
                                float alpha, int node, int f8, float* yv) {
    int deg = cnt[node];
    float dv = rsqrtf((float)(deg + 1));
    const int* row = &csrc[(size_t)node * CAP];

    float acc[8] = {};
    acc_row_w(acc, *(const uint4*)&Tb[(size_t)node * DD + f8], dv);  // self-loop

    int k = 0;
    for (; k + 4 <= deg; k += 4) {
        int4 ss = *(const int4*)&row[k];
        float w0 = rsqrtf((float)(cnt[ss.x] + 1));
        float w1 = rsqrtf((float)(cnt[ss.y] + 1));
        float w2 = rsqrtf((float)(cnt[ss.z] + 1));
        float w3 = rsqrtf((float)(cnt[ss.w] + 1));
        uint4 t0 = *(const uint4*)&Tb[(size_t)ss.x * DD + f8];
        uint4 t1 = *(const uint4*)&Tb[(size_t)ss.y * DD + f8];
        uint4 t2 = *(const uint4*)&Tb[(size_t)ss.z * DD + f8];
        uint4 t3 = *(const uint4*)&Tb[(size_t)ss.w * DD + f8];
        acc_row_w(acc, t0, w0); acc_row_w(acc, t1, w1);
        acc_row_w(acc, t2, w2); acc_row_w(acc, t3, w3);
    }
    for (; k < deg; k++) {
        int s = row[k];
        float w = rsqrtf((float)(cnt[s] + 1));
        acc_row_w(acc, *(const uint4*)&Tb[(size_t)s * DD + f8], w);
    }

    float a[8];
    float s1 = 0.f, s2 = 0.f;
    #pragma unroll
    for (int q = 0; q < 8; q++) {
        a[q] = fmaf(acc[q], dv, bv[q]);
        s1 += a[q]; s2 += a[q] * a[q];
    }
    #pragma unroll
    for (int off = 8; off > 0; off >>= 1) {
        s1 += __shfl_xor(s1, off, 16);
        s2 += __shfl_xor(s2, off, 16);
    }
    float mu = s1 * (1.f / DD);
    float var = s2 * (1.f / DD) - mu * mu;
    float rstd = rsqrtf(var + LN_EPS);
    #pragma unroll
    for (int q = 0; q < 8; q++) {
        float y = (a[q] - mu) * rstd * wv[q] + cv[q];
        yv[q] = (y >= 0.f) ? y : alpha * y;
    }
}

// ------- fused agg(layer l) + gemm(layer l+1): Tb -> Tout (both UNSCALED) ---
// 256 threads, 16 nodes/block (3125 blocks = max TLP). 16 groups x 16 lanes,
// one node per group. MFMA: 4 waves, wave w does the 16-row x 32-col slice.

__global__ __launch_bounds__(256) void aggemm_kernel(
    const unsigned short* __restrict__ Tb, const int* __restrict__ cnt,
    const int* __restrict__ csrc,
    const float* __restrict__ bias, const float* __restrict__ lnw,
    const float* __restrict__ lnb, const float* __restrict__ alphas, int layer,
    const unsigned short* __restrict__ Wt, unsigned short* __restrict__ Tout) {
    __shared__ unsigned short alds[POOL * ALD];
    int tid = threadIdx.x;
    int g = tid >> 4;
    int lane16 = tid & 15;
    int f8 = lane16 * 8;
    int nodebase = blockIdx.x * POOL;

    float4 b0 = *(const float4*)&bias[f8];
    float4 b1 = *(const float4*)&bias[f8 + 4];
    float4 w0 = *(const float4*)&lnw[f8];
    float4 w1 = *(const float4*)&lnw[f8 + 4];
    float4 c0 = *(const float4*)&lnb[f8];
    float4 c1 = *(const float4*)&lnb[f8 + 4];
    float bv[8] = {b0.x, b0.y, b0.z, b0.w, b1.x, b1.y, b1.z, b1.w};
    float wv[8] = {w0.x, w0.y, w0.z, w0.w, w1.x, w1.y, w1.z, w1.w};
    float cv[8] = {c0.x, c0.y, c0.z, c0.w, c1.x, c1.y, c1.z, c1.w};
    float alpha = alphas[layer];

    {   // NN == 3125*16: node always in range
        int node = nodebase + g;
        float yv[8];
        agg_node(Tb, cnt, csrc, bv, wv, cv, alpha, node, f8, yv);
        unsigned short pv[8];
        #pragma unroll
        for (int q = 0; q < 8; q++) pv[q] = f2bf(yv[q]);
        *(uint4*)&alds[g * ALD + f8] = *(uint4*)&pv[0];
    }
    __syncthreads();

    // MFMA: C = Y @ W_{l+1} (unscaled out). 4 waves, 16x32 each.
    int lane = tid & 63;
    int w = tid >> 6;                 // 0..3
    int cbase = w * 32;
    int kq = (lane >> 4) * 8;
    int mrow = lane & 15;
    floatx4 acc[2] = {{0.f,0.f,0.f,0.f},{0.f,0.f,0.f,0.f}};
    #pragma unroll
    for (int t = 0; t < 4; t++) {
        short8 a = *(const short8*)&alds[mrow * ALD + t * 32 + kq];
        #pragma unroll
        for (int j = 0; j < 2; j++) {
            short8 b = *(const short8*)&Wt[(cbase + j * 16 + (lane & 15)) * DD + t * 32 + kq];
            acc[j] = __builtin_amdgcn_mfma_f32_16x16x32_bf16(a, b, acc[j], 0, 0, 0);
        }
    }
    int gnode0 = nodebase + (lane >> 4) * 4;
    #pragma unroll
    for (int i = 0; i < 4; i++) {
        int node = gnode0 + i;
        #pragma unroll
        for (int j = 0; j < 2; j++)
            Tout[(size_t)node * DD + cbase + j * 16 + (lane & 15)] = f2bf(acc[j][i]);
    }
}

// ---------------- final agg: layer 2, f32 output ----------------
// 256 threads = 16 groups of 16 lanes; group g handles node blockIdx*16+g.

__global__ __launch_bounds__(256) void agg_final_kernel(
    const unsigned short* __restrict__ Tb, const int* __restrict__ cnt,
    const int* __restrict__ csrc,
    const float* __restrict__ bias, const float* __restrict__ lnw,
    const float* __restrict__ lnb, const float* __restrict__ alphas, int layer,
    float* __restrict__ out) {
    int g = threadIdx.x >> 4;
    int lane16 = threadIdx.x & 15;
    int f8 = lane16 * 8;
    int node = blockIdx.x * 16 + g;
    if (node >= NN) return;

    float4 b0 = *(const float4*)&bias[f8];
    float4 b1 = *(const float4*)&bias[f8 + 4];
    float4 w0 = *(const float4*)&lnw[f8];
    float4 w1 = *(const float4*)&lnw[f8 + 4];
    float4 c0 = *(const float4*)&lnb[f8];
    float4 c1 = *(const float4*)&lnb[f8 + 4];
    float bv[8] = {b0.x, b0.y, b0.z, b0.w, b1.x, b1.y, b1.z, b1.w};
    float wv[8] = {w0.x, w0.y, w0.z, w0.w, w1.x, w1.y, w1.z, w1.w};
    float cv[8] = {c0.x, c0.y, c0.z, c0.w, c1.x, c1.y, c1.z, c1.w};

    float yv[8];
    agg_node(Tb, cnt, csrc, bv, wv, cv, alphas[layer], node, f8, yv);

    float* op = &out[(size_t)node * DD + f8];
    *(float4*)&op[0] = make_float4(yv[0], yv[1], yv[2], yv[3]);
    *(float4*)&op[4] = make_float4(yv[4], yv[5], yv[6], yv[7]);
}

// ---------------- launch ----------------

extern "C" void kernel_launch(void* const* d_in, const int* in_sizes, int n_in,
                              void* d_out, int out_size, void* d_ws, size_t ws_size,
                              hipStream_t stream) {
    const float* x    = (const float*)d_in[0];
    const int*   ei   = (const int*)d_in[1];
    const float* Ws   = (const float*)d_in[2];
    const float* bs   = (const float*)d_in[3];
    const float* lnw  = (const float*)d_in[4];
    const float* lnb  = (const float*)d_in[5];
    const float* alphas = (const float*)d_in[6];
    float* out = (float*)d_out;

    const int* src = ei;
    const int* dst = ei + EE;

    char* ws = (char*)d_ws;
    size_t off = 0;
    auto alloc = [&](size_t bytes) -> void* {
        void* p = ws + off;
        off = (off + bytes + 255) & ~(size_t)255;
        return p;
    };
    int* cnt  = (int*)alloc(NN * sizeof(int));
    int* csrc = (int*)alloc((size_t)NN * CAP * sizeof(int));
    unsigned short* wt    = (unsigned short*)alloc((size_t)LL * DD * DD * sizeof(unsigned short));
    unsigned short* tbufA = (unsigned short*)alloc((size_t)NN * DD * sizeof(unsigned short));
    unsigned short* tbufB = (unsigned short*)alloc((size_t)NN * DD * sizeof(unsigned short));

    init_kernel<<<256, 256, 0, stream>>>(Ws, wt, cnt);
    gemm0_fill_kernel<<<G0BLK, 256, 0, stream>>>(x, wt, src, dst, cnt, csrc, tbufA);

    const int agg_grid = NN / POOL;   // 3125
    aggemm_kernel<<<agg_grid, 256, 0, stream>>>(tbufA, cnt, csrc,
                                                bs + 0 * DD, lnw + 0 * DD, lnb + 0 * DD,
                                                alphas, 0, wt + 1 * DD * DD, tbufB);
    aggemm_kernel<<<agg_grid, 256, 0, stream>>>(tbufB, cnt, csrc,
                                                bs + 1 * DD, lnw + 1 * DD, lnb + 1 * DD,
                                                alphas, 1, wt + 2 * DD * DD, tbufA);
    agg_final_kernel<<<(NN + 15) / 16, 256, 0, stream>>>(tbufA, cnt, csrc,
                                                         bs + 2 * DD, lnw + 2 * DD, lnb + 2 * DD,
                                                         alphas, 2, out);
}

// Round 14
// 231.347 us; speedup vs baseline: 1.1009x; 1.0194x over previous
//
#include <hip/hip_runtime.h>
#include <hip/hip_bf16.h>

#define NN 50000
#define EE 600000
#define DD 128
#define LL 3
#define LN_EPS 1e-5f
#define CAP 64                      // bucket capacity; max in-degree ~30 for this graph
#define ALD 136                     // padded LDS row stride (shorts)
#define POOL 16                     // nodes per block tile (NN = 3125 * 16 exactly)
#define NBLKS (NN / POOL)           // 3125; 3125*256 = 800000 >= EE (single-shot fill)

typedef __attribute__((ext_vector_type(8))) short short8;
typedef __attribute__((ext_vector_type(4))) float floatx4;

__device__ inline unsigned short f2bf(float f) {
    union { float f; unsigned u; } a; a.f = f;
    unsigned r = a.u + 0x7fffu + ((a.u >> 16) & 1u);  // RNE (finite values)
    return (unsigned short)(r >> 16);
}

// ------- init: zero cnt + W -> Wt bf16 (Wt[l][n][k] = bf16(W[l][k][n])) -----

__global__ __launch_bounds__(256) void init_kernel(const float* __restrict__ W,
                                                   unsigned short* __restrict__ Wt,
                                                   int* __restrict__ cnt) {
    for (int i = blockIdx.x * 256 + threadIdx.x; i < NN; i += gridDim.x * 256)
        cnt[i] = 0;
    for (int i = blockIdx.x * 256 + threadIdx.x; i < LL * DD * DD; i += gridDim.x * 256) {
        int l = i >> 14, n = (i >> 7) & 127, k = i & 127;
        Wt[i] = f2bf(W[(l << 14) + k * DD + n]);
    }
}

// ------ gemm0_fill: single-shot bucket-CSR fill + Tb = bf16(x @ W0) ---------
// 3125 blocks x 256 thr (16-row tile): max TLP for the latency-bound fill.
// MFMA: 4 waves, wave w does 16 rows x 32 cols. Epilogue via LDS transpose ->
// coalesced dwordx4 stores.

__global__ __launch_bounds__(256) void gemm0_fill_kernel(
    const float* __restrict__ A, const unsigned short* __restrict__ Wt,
    const int* __restrict__ src, const int* __restrict__ dst,
    int* __restrict__ cnt, int* __restrict__ csrc,
    unsigned short* __restrict__ Cb) {
    __shared__ unsigned short alds[POOL * ALD];
    int tid = threadIdx.x;
    int lane = tid & 63;
    int w = tid >> 6;

    // phase A: CSR fill, one edge per thread (grid covers all EE)
    {
        int e = blockIdx.x * 256 + tid;
        if (e < EE) {
            int d = dst[e];
            int pos = atomicAdd(&cnt[d], 1);
            csrc[(size_t)d * CAP + pos] = src[e];
        }
    }

    // phase B: stage 16 rows of x (f32 -> bf16) into LDS
    {
        int row = tid >> 4;
        int kc = (tid & 15) * 8;
        const float* ap = &A[(size_t)(blockIdx.x * POOL + row) * DD + kc];
        float4 v0 = *(const float4*)&ap[0];
        float4 v1 = *(const float4*)&ap[4];
        float fv[8] = {v0.x, v0.y, v0.z, v0.w, v1.x, v1.y, v1.z, v1.w};
        unsigned short uv[8];
        #pragma unroll
        for (int q = 0; q < 8; q++) uv[q] = f2bf(fv[q]);
        *(uint4*)&alds[row * ALD + kc] = *(uint4*)&uv[0];
    }
    __syncthreads();

    // MFMA: 4 waves, 16x32 slice each
    int cbase = w * 32;
    int kq = (lane >> 4) * 8;
    int mrow = lane & 15;
    floatx4 acc[2] = {{0.f,0.f,0.f,0.f},{0.f,0.f,0.f,0.f}};
    #pragma unroll
    for (int t = 0; t < 4; t++) {
        short8 a = *(const short8*)&alds[mrow * ALD + t * 32 + kq];
        #pragma unroll
        for (int j = 0; j < 2; j++) {
            short8 b = *(const short8*)&Wt[(cbase + j * 16 + (lane & 15)) * DD + t * 32 + kq];
            acc[j] = __builtin_amdgcn_mfma_f32_16x16x32_bf16(a, b, acc[j], 0, 0, 0);
        }
    }
    __syncthreads();   // alds reads done before transpose overwrites

    // epilogue: transpose through LDS, then coalesced stores
    {
        int r0 = (lane >> 4) * 4;
        #pragma unroll
        for (int i = 0; i < 4; i++)
            #pragma unroll
            for (int j = 0; j < 2; j++)
                alds[(r0 + i) * ALD + cbase + j * 16 + (lane & 15)] = f2bf(acc[j][i]);
    }
    __syncthreads();
    {
        int srow = tid >> 4;
        int scol = (tid & 15) * 8;
        *(uint4*)&Cb[(size_t)(blockIdx.x * POOL + srow) * DD + scol] =
            *(uint4*)&alds[srow * ALD + scol];
    }
}

// --------- shared agg helper: aggregate+bias+LN+PReLU for one node ----------
// Tb is UNSCALED; per-edge weight w = rsqrt(cnt[s]+1), self term seeded dv*T.
// 16-lane group; lane owns features [8l,8l+8). Returns yv[8] (f32).

__device__ inline void acc_row_w(float* acc, uint4 t, float w) {
    unsigned uu[4] = {t.x, t.y, t.z, t.w};
    #pragma unroll
    for (int q = 0; q < 4; q++) {
        union { unsigned x; float f; } lo, hi;
        lo.x = uu[q] << 16;
        hi.x = uu[q] & 0xffff0000u;
        acc[2 * q]     += w * lo.f;
        acc[2 * q + 1] += w * hi.f;
    }
}

__device__ inline void agg_node(const unsigned short* __restrict__ Tb,
                                const int* __restrict__ cnt, const int* __restrict__ csrc,
                                const float* bv, const float* wv, const float* cv,
                                float alpha, int node, int f8, float* yv) {
    int deg = cnt[node];
    float dv = rsqrtf((float)(deg + 1));
    const int* row = &csrc[(size_t)node * CAP];

    float acc[8] = {};
    acc_row_w(acc, *(const uint4*)&Tb[(size_t)node * DD + f8], dv);  // self-loop

    int k = 0;
    for (; k + 4 <= deg; k += 4) {
        int4 ss = *(const int4*)&row[k];
        float w0 = rsqrtf((float)(cnt[ss.x] + 1));
        float w1 = rsqrtf((float)(cnt[ss.y] + 1));
        float w2 = rsqrtf((float)(cnt[ss.z] + 1));
        float w3 = rsqrtf((float)(cnt[ss.w] + 1));
        uint4 t0 = *(const uint4*)&Tb[(size_t)ss.x * DD + f8];
        uint4 t1 = *(const uint4*)&Tb[(size_t)ss.y * DD + f8];
        uint4 t2 = *(const uint4*)&Tb[(size_t)ss.z * DD + f8];
        uint4 t3 = *(const uint4*)&Tb[(size_t)ss.w * DD + f8];
        acc_row_w(acc, t0, w0); acc_row_w(acc, t1, w1);
        acc_row_w(acc, t2, w2); acc_row_w(acc, t3, w3);
    }
    for (; k < deg; k++) {
        int s = row[k];
        float w = rsqrtf((float)(cnt[s] + 1));
        acc_row_w(acc, *(const uint4*)&Tb[(size_t)s * DD + f8], w);
    }

    float a[8];
    float s1 = 0.f, s2 = 0.f;
    #pragma unroll
    for (int q = 0; q < 8; q++) {
        a[q] = fmaf(acc[q], dv, bv[q]);
        s1 += a[q]; s2 += a[q] * a[q];
    }
    #pragma unroll
    for (int off = 8; off > 0; off >>= 1) {
        s1 += __shfl_xor(s1, off, 16);
        s2 += __shfl_xor(s2, off, 16);
    }
    float mu = s1 * (1.f / DD);
    float var = s2 * (1.f / DD) - mu * mu;
    float rstd = rsqrtf(var + LN_EPS);
    #pragma unroll
    for (int q = 0; q < 8; q++) {
        float y = (a[q] - mu) * rstd * wv[q] + cv[q];
        yv[q] = (y >= 0.f) ? y : alpha * y;
    }
}

// ------- fused agg(layer l) + gemm(layer l+1): Tb -> Tout (both UNSCALED) ---
// 256 threads, 16 nodes/block (3125 blocks = max TLP). MFMA 4 waves 16x32;
// epilogue via LDS transpose -> coalesced dwordx4 stores.

__global__ __launch_bounds__(256) void aggemm_kernel(
    const unsigned short* __restrict__ Tb, const int* __restrict__ cnt,
    const int* __restrict__ csrc,
    const float* __restrict__ bias, const float* __restrict__ lnw,
    const float* __restrict__ lnb, const float* __restrict__ alphas, int layer,
    const unsigned short* __restrict__ Wt, unsigned short* __restrict__ Tout) {
    __shared__ unsigned short alds[POOL * ALD];
    int tid = threadIdx.x;
    int g = tid >> 4;
    int lane16 = tid & 15;
    int f8 = lane16 * 8;
    int nodebase = blockIdx.x * POOL;

    float4 b0 = *(const float4*)&bias[f8];
    float4 b1 = *(const float4*)&bias[f8 + 4];
    float4 w0 = *(const float4*)&lnw[f8];
    float4 w1 = *(const float4*)&lnw[f8 + 4];
    float4 c0 = *(const float4*)&lnb[f8];
    float4 c1 = *(const float4*)&lnb[f8 + 4];
    float bv[8] = {b0.x, b0.y, b0.z, b0.w, b1.x, b1.y, b1.z, b1.w};
    float wv[8] = {w0.x, w0.y, w0.z, w0.w, w1.x, w1.y, w1.z, w1.w};
    float cv[8] = {c0.x, c0.y, c0.z, c0.w, c1.x, c1.y, c1.z, c1.w};
    float alpha = alphas[layer];

    {   // NN == 3125*16: node always in range
        int node = nodebase + g;
        float yv[8];
        agg_node(Tb, cnt, csrc, bv, wv, cv, alpha, node, f8, yv);
        unsigned short pv[8];
        #pragma unroll
        for (int q = 0; q < 8; q++) pv[q] = f2bf(yv[q]);
        *(uint4*)&alds[g * ALD + f8] = *(uint4*)&pv[0];
    }
    __syncthreads();

    // MFMA: C = Y @ W_{l+1} (unscaled out). 4 waves, 16x32 each.
    int lane = tid & 63;
    int w = tid >> 6;                 // 0..3
    int cbase = w * 32;
    int kq = (lane >> 4) * 8;
    int mrow = lane & 15;
    floatx4 acc[2] = {{0.f,0.f,0.f,0.f},{0.f,0.f,0.f,0.f}};
    #pragma unroll
    for (int t = 0; t < 4; t++) {
        short8 a = *(const short8*)&alds[mrow * ALD + t * 32 + kq];
        #pragma unroll
        for (int j = 0; j < 2; j++) {
            short8 b = *(const short8*)&Wt[(cbase + j * 16 + (lane & 15)) * DD + t * 32 + kq];
            acc[j] = __builtin_amdgcn_mfma_f32_16x16x32_bf16(a, b, acc[j], 0, 0, 0);
        }
    }
    __syncthreads();   // alds reads done before transpose overwrites

    {
        int r0 = (lane >> 4) * 4;
        #pragma unroll
        for (int i = 0; i < 4; i++)
            #pragma unroll
            for (int j = 0; j < 2; j++)
                alds[(r0 + i) * ALD + cbase + j * 16 + (lane & 15)] = f2bf(acc[j][i]);
    }
    __syncthreads();
    {
        int srow = tid >> 4;
        int scol = (tid & 15) * 8;
        *(uint4*)&Tout[(size_t)(nodebase + srow) * DD + scol] =
            *(uint4*)&alds[srow * ALD + scol];
    }
}

// ---------------- final agg: layer 2, f32 output ----------------
// 256 threads = 16 groups of 16 lanes; group g handles node blockIdx*16+g.

__global__ __launch_bounds__(256) void agg_final_kernel(
    const unsigned short* __restrict__ Tb, const int* __restrict__ cnt,
    const int* __restrict__ csrc,
    const float* __restrict__ bias, const float* __restrict__ lnw,
    const float* __restrict__ lnb, const float* __restrict__ alphas, int layer,
    float* __restrict__ out) {
    int g = threadIdx.x >> 4;
    int lane16 = threadIdx.x & 15;
    int f8 = lane16 * 8;
    int node = blockIdx.x * 16 + g;

    float4 b0 = *(const float4*)&bias[f8];
    float4 b1 = *(const float4*)&bias[f8 + 4];
    float4 w0 = *(const float4*)&lnw[f8];
    float4 w1 = *(const float4*)&lnw[f8 + 4];
    float4 c0 = *(const float4*)&lnb[f8];
    float4 c1 = *(const float4*)&lnb[f8 + 4];
    float bv[8] = {b0.x, b0.y, b0.z, b0.w, b1.x, b1.y, b1.z, b1.w};
    float wv[8] = {w0.x, w0.y, w0.z, w0.w, w1.x, w1.y, w1.z, w1.w};
    float cv[8] = {c0.x, c0.y, c0.z, c0.w, c1.x, c1.y, c1.z, c1.w};

    float yv[8];
    agg_node(Tb, cnt, csrc, bv, wv, cv, alphas[layer], node, f8, yv);

    float* op = &out[(size_t)node * DD + f8];
    *(float4*)&op[0] = make_float4(yv[0], yv[1], yv[2], yv[3]);
    *(float4*)&op[4] = make_float4(yv[4], yv[5], yv[6], yv[7]);
}

// ---------------- launch ----------------

extern "C" void kernel_launch(void* const* d_in, const int* in_sizes, int n_in,
                              void* d_out, int out_size, void* d_ws, size_t ws_size,
                              hipStream_t stream) {
    const float* x    = (const float*)d_in[0];
    const int*   ei   = (const int*)d_in[1];
    const float* Ws   = (const float*)d_in[2];
    const float* bs   = (const float*)d_in[3];
    const float* lnw  = (const float*)d_in[4];
    const float* lnb  = (const float*)d_in[5];
    const float* alphas = (const float*)d_in[6];
    float* out = (float*)d_out;

    const int* src = ei;
    const int* dst = ei + EE;

    char* ws = (char*)d_ws;
    size_t off = 0;
    auto alloc = [&](size_t bytes) -> void* {
        void* p = ws + off;
        off = (off + bytes + 255) & ~(size_t)255;
        return p;
    };
    int* cnt  = (int*)alloc(NN * sizeof(int));
    int* csrc = (int*)alloc((size_t)NN * CAP * sizeof(int));
    unsigned short* wt    = (unsigned short*)alloc((size_t)LL * DD * DD * sizeof(unsigned short));
    unsigned short* tbufA = (unsigned short*)alloc((size_t)NN * DD * sizeof(unsigned short));
    unsigned short* tbufB = (unsigned short*)alloc((size_t)NN * DD * sizeof(unsigned short));

    init_kernel<<<256, 256, 0, stream>>>(Ws, wt, cnt);
    gemm0_fill_kernel<<<NBLKS, 256, 0, stream>>>(x, wt, src, dst, cnt, csrc, tbufA);

    aggemm_kernel<<<NBLKS, 256, 0, stream>>>(tbufA, cnt, csrc,
                                             bs + 0 * DD, lnw + 0 * DD, lnb + 0 * DD,
                                             alphas, 0, wt + 1 * DD * DD, tbufB);
    aggemm_kernel<<<NBLKS, 256, 0, stream>>>(tbufB, cnt, csrc,
                                             bs + 1 * DD, lnw + 1 * DD, lnb + 1 * DD,
                                             alphas, 1, wt + 2 * DD * DD, tbufA);
    agg_final_kernel<<<NBLKS, 256, 0, stream>>>(tbufA, cnt, csrc,
                                                bs + 2 * DD, lnw + 2 * DD, lnb + 2 * DD,
                                                alphas, 2, out);
}